// Round 1
// baseline (65071.954 us; speedup 1.0000x reference)
//
#include <hip/hip_runtime.h>
#include <hip/hip_bf16.h>

#define H      1024
#define IN_DIM 512
#define OD     512
#define T_LEN  16384
#define NBLK   256   // workgroups in recurrence kernel
#define UPW    4     // hidden units per workgroup (one per wave)

typedef unsigned long long u64;
typedef unsigned int u32;
typedef unsigned short ushort8 __attribute__((ext_vector_type(8)));

__device__ __forceinline__ unsigned short f2bf(float f) {
    u32 u = __float_as_uint(f);
    u32 r = (u + 0x7fffu + ((u >> 16) & 1u)) >> 16;   // RNE
    return (unsigned short)r;
}
__device__ __forceinline__ float bf2f(unsigned short s) {
    return __uint_as_float(((u32)s) << 16);
}

// Persistent GRU recurrence. Grid = 256 WGs x 256 threads (cooperative).
// WG wg owns hidden units u0..u0+3 (one per wave). Weights live in LDS (bf16).
// h state is exchanged through (tag,value) 8B atomic pairs at agent scope:
// pairs[parity][unit] = (tag<<32)|f32bits. Tag T == h after T steps. Step t
// reads parity t&1 (tag==t), writes parity (t+1)&1 with tag t+1.
__global__ __launch_bounds__(256, 1)
void gru_rec_kernel(const float* __restrict__ X,
                    const float* __restrict__ Wih,
                    const float* __restrict__ Whh,
                    const float* __restrict__ bih,
                    const float* __restrict__ bhh,
                    float* __restrict__ hs,
                    u64* __restrict__ pairs)   // [2][H]
{
    __shared__ unsigned short sWhh[3][UPW][H];      // 24 KB
    __shared__ unsigned short sWih[3][UPW][IN_DIM]; // 12 KB
    __shared__ float hsh[H];                        // 4 KB

    const int tid  = threadIdx.x;
    const int wave = tid >> 6;
    const int lane = tid & 63;
    const int wg   = blockIdx.x;
    const int u0   = wg * UPW;
    const int u    = u0 + wave;      // this wave's hidden unit

    // ---- stage weights into LDS (bf16) ----
    for (int r = 0; r < 3 * UPW; ++r) {
        const int g = r >> 2, i = r & 3;
        const size_t grow = (size_t)g * H + (size_t)(u0 + i);
        float4 v = ((const float4*)(Whh + grow * H))[tid];        // 256*4 = 1024
        unsigned short* dh = &sWhh[g][i][tid * 4];
        dh[0] = f2bf(v.x); dh[1] = f2bf(v.y); dh[2] = f2bf(v.z); dh[3] = f2bf(v.w);
        if (tid < 128) {
            float4 w = ((const float4*)(Wih + grow * IN_DIM))[tid]; // 128*4 = 512
            unsigned short* dx = &sWih[g][i][tid * 4];
            dx[0] = f2bf(w.x); dx[1] = f2bf(w.y); dx[2] = f2bf(w.z); dx[3] = f2bf(w.w);
        }
    }
    const float bxr = bih[u],       bxz = bih[H + u],     bxn = bih[2 * H + u];
    const float bhr = bhh[u],       bhz = bhh[H + u],     bhn = bhh[2 * H + u];
    __syncthreads();

    // ---- prefetch x row for t=0 (cols lane*8 .. +8) ----
    float xv[8], xw[8];
    {
        const float4* xp = (const float4*)X;
        float4 a = xp[lane * 2], b = xp[lane * 2 + 1];
        xv[0]=a.x; xv[1]=a.y; xv[2]=a.z; xv[3]=a.w;
        xv[4]=b.x; xv[5]=b.y; xv[6]=b.z; xv[7]=b.w;
    }

    const int base = tid * 4;          // pairs polled by this thread
    const int hoff = lane * 16;        // h columns consumed by this lane
    const int xoff = lane * 8;

    #pragma unroll 1
    for (int t = 0; t < T_LEN; ++t) {
        // prefetch next x row (in flight during the spin)
        {
            const int tn = (t + 1 < T_LEN) ? (t + 1) : t;
            const float4* xp = (const float4*)(X + (size_t)tn * IN_DIM);
            float4 a = xp[lane * 2], b = xp[lane * 2 + 1];
            xw[0]=a.x; xw[1]=a.y; xw[2]=a.z; xw[3]=a.w;
            xw[4]=b.x; xw[5]=b.y; xw[6]=b.z; xw[7]=b.w;
        }

        // ---- spin: wait for my 4 h pairs of this step (wave-coalesced) ----
        u64* pp = pairs + (size_t)(t & 1) * H;
        const u32 want = (u32)t;
        u64 p0, p1, p2, p3;
        for (;;) {
            p0 = __hip_atomic_load(pp + base + 0, __ATOMIC_RELAXED, __HIP_MEMORY_SCOPE_AGENT);
            p1 = __hip_atomic_load(pp + base + 1, __ATOMIC_RELAXED, __HIP_MEMORY_SCOPE_AGENT);
            p2 = __hip_atomic_load(pp + base + 2, __ATOMIC_RELAXED, __HIP_MEMORY_SCOPE_AGENT);
            p3 = __hip_atomic_load(pp + base + 3, __ATOMIC_RELAXED, __HIP_MEMORY_SCOPE_AGENT);
            if ((u32)(p0 >> 32) == want && (u32)(p1 >> 32) == want &&
                (u32)(p2 >> 32) == want && (u32)(p3 >> 32) == want) break;
        }
        {
            float4 hv4 = make_float4(__uint_as_float((u32)p0), __uint_as_float((u32)p1),
                                     __uint_as_float((u32)p2), __uint_as_float((u32)p3));
            *(float4*)&hsh[base] = hv4;
        }
        __syncthreads();   // hsh complete

        // ---- gather my 16 h values ----
        float hv[16];
        #pragma unroll
        for (int i = 0; i < 4; ++i) {
            float4 h4 = *(const float4*)&hsh[hoff + i * 4];
            hv[i*4+0]=h4.x; hv[i*4+1]=h4.y; hv[i*4+2]=h4.z; hv[i*4+3]=h4.w;
        }

        // ---- partial dots: gh (3 gates x 16 cols) + gx (3 gates x 8 cols) ----
        float ar = 0.f, az = 0.f, anh = 0.f, anx = 0.f;
        {
            const ushort8 r0 = *(const ushort8*)&sWhh[0][wave][hoff];
            const ushort8 r1 = *(const ushort8*)&sWhh[0][wave][hoff + 8];
            const ushort8 z0 = *(const ushort8*)&sWhh[1][wave][hoff];
            const ushort8 z1 = *(const ushort8*)&sWhh[1][wave][hoff + 8];
            const ushort8 n0 = *(const ushort8*)&sWhh[2][wave][hoff];
            const ushort8 n1 = *(const ushort8*)&sWhh[2][wave][hoff + 8];
            #pragma unroll
            for (int i = 0; i < 8; ++i) {
                ar  += bf2f(r0[i]) * hv[i];     ar  += bf2f(r1[i]) * hv[8 + i];
                az  += bf2f(z0[i]) * hv[i];     az  += bf2f(z1[i]) * hv[8 + i];
                anh += bf2f(n0[i]) * hv[i];     anh += bf2f(n1[i]) * hv[8 + i];
            }
            const ushort8 xr = *(const ushort8*)&sWih[0][wave][xoff];
            const ushort8 xz = *(const ushort8*)&sWih[1][wave][xoff];
            const ushort8 xn = *(const ushort8*)&sWih[2][wave][xoff];
            #pragma unroll
            for (int i = 0; i < 8; ++i) {
                ar  += bf2f(xr[i]) * xv[i];
                az  += bf2f(xz[i]) * xv[i];
                anx += bf2f(xn[i]) * xv[i];
            }
        }

        // ---- wave reduction ----
        #pragma unroll
        for (int off = 32; off > 0; off >>= 1) {
            ar  += __shfl_xor(ar,  off, 64);
            az  += __shfl_xor(az,  off, 64);
            anh += __shfl_xor(anh, off, 64);
            anx += __shfl_xor(anx, off, 64);
        }

        // ---- gates + publish (lane 0 of each wave) ----
        if (lane == 0) {
            const float hprev = hsh[u];
            const float r = 1.f / (1.f + __expf(-(ar + bxr + bhr)));
            const float z = 1.f / (1.f + __expf(-(az + bxz + bhz)));
            const float n = tanhf(anx + bxn + r * (anh + bhn));
            const float hnew = (1.f - z) * n + z * hprev;
            hs[(size_t)t * H + u] = hnew;
            const u64 pk = ((u64)(u32)(t + 1) << 32) | (u64)__float_as_uint(hnew);
            __hip_atomic_store(pairs + (size_t)((t + 1) & 1) * H + u, pk,
                               __ATOMIC_RELAXED, __HIP_MEMORY_SCOPE_AGENT);
        }
        __syncthreads();   // protect hsh from next-iteration overwrite

        #pragma unroll
        for (int i = 0; i < 8; ++i) xv[i] = xw[i];
    }
}

// out[m,n] = sum_k hs[m,k] * Wfc[n,k] + bfc[n]   (M=16384, N=512, K=1024)
#define BM 64
#define BN 64
#define BK 16
__global__ __launch_bounds__(256)
void fc_kernel(const float* __restrict__ A, const float* __restrict__ B,
               const float* __restrict__ bias, float* __restrict__ C)
{
    __shared__ float As[BK][BM + 4];
    __shared__ float Bs[BK][BN + 4];
    const int tid = threadIdx.x;
    const int m0 = blockIdx.y * BM, n0 = blockIdx.x * BN;
    const int tx = tid & 15, ty = tid >> 4;
    float acc[4][4] = {};
    const int r = tid >> 2, c = (tid & 3) << 2;
    for (int k0 = 0; k0 < H; k0 += BK) {
        float4 va = *(const float4*)(A + (size_t)(m0 + r) * H + (k0 + c));
        As[c + 0][r] = va.x; As[c + 1][r] = va.y; As[c + 2][r] = va.z; As[c + 3][r] = va.w;
        float4 vb = *(const float4*)(B + (size_t)(n0 + r) * H + (k0 + c));
        Bs[c + 0][r] = vb.x; Bs[c + 1][r] = vb.y; Bs[c + 2][r] = vb.z; Bs[c + 3][r] = vb.w;
        __syncthreads();
        #pragma unroll
        for (int kk = 0; kk < BK; ++kk) {
            float4 a4 = *(const float4*)&As[kk][ty * 4];
            float4 b4 = *(const float4*)&Bs[kk][tx * 4];
            const float av[4] = {a4.x, a4.y, a4.z, a4.w};
            const float bv[4] = {b4.x, b4.y, b4.z, b4.w};
            #pragma unroll
            for (int i = 0; i < 4; ++i)
                #pragma unroll
                for (int j = 0; j < 4; ++j)
                    acc[i][j] += av[i] * bv[j];
        }
        __syncthreads();
    }
    #pragma unroll
    for (int i = 0; i < 4; ++i) {
        const int m = m0 + ty * 4 + i;
        #pragma unroll
        for (int j = 0; j < 4; ++j) {
            const int n = n0 + tx * 4 + j;
            C[(size_t)m * OD + n] = acc[i][j] + bias[n];
        }
    }
}

extern "C" void kernel_launch(void* const* d_in, const int* in_sizes, int n_in,
                              void* d_out, int out_size, void* d_ws, size_t ws_size,
                              hipStream_t stream) {
    const float* X   = (const float*)d_in[0];
    const float* Wih = (const float*)d_in[1];
    const float* Whh = (const float*)d_in[2];
    const float* bih = (const float*)d_in[3];
    const float* bhh = (const float*)d_in[4];
    const float* Wfc = (const float*)d_in[5];
    const float* bfc = (const float*)d_in[6];
    float* out = (float*)d_out;

    float* hs   = (float*)d_ws;                                   // 16384*1024*4 = 64 MB
    u64*   pairs = (u64*)((char*)d_ws + (size_t)T_LEN * H * 4);   // 2*1024*8 = 16 KB

    // tag 0 / value 0.0 == initial hidden state
    hipMemsetAsync(pairs, 0, 2 * H * sizeof(u64), stream);

    void* args[] = { (void*)&X, (void*)&Wih, (void*)&Whh, (void*)&bih,
                     (void*)&bhh, (void*)&hs, (void*)&pairs };
    hipError_t e = hipLaunchCooperativeKernel((const void*)gru_rec_kernel,
                                              dim3(NBLK), dim3(256), args, 0, stream);
    if (e != hipSuccess) {
        // fallback: plain launch (256 WGs / 256 CUs, 40KB LDS -> co-resident in practice)
        gru_rec_kernel<<<dim3(NBLK), dim3(256), 0, stream>>>(X, Wih, Whh, bih, bhh, hs, pairs);
    }

    dim3 fgrid(OD / BN, T_LEN / BM);
    fc_kernel<<<fgrid, dim3(256), 0, stream>>>(hs, Wfc, bfc, out);
}

// Round 3
// 53685.919 us; speedup vs baseline: 1.2121x; 1.2121x over previous
//
#include <hip/hip_runtime.h>
#include <hip/hip_bf16.h>

#define H      1024
#define IN_DIM 512
#define OD     512
#define T_LEN  16384
#define NBLK   256   // compute workgroups (sequencer is WG NBLK)
#define UPW    4     // hidden units per workgroup (one per wave)

typedef unsigned long long u64;
typedef unsigned int u32;
typedef unsigned short ushort8 __attribute__((ext_vector_type(8)));

__device__ __forceinline__ unsigned short f2bf(float f) {
    u32 u = __float_as_uint(f);
    u32 r = (u + 0x7fffu + ((u >> 16) & 1u)) >> 16;   // RNE
    return (unsigned short)r;
}
__device__ __forceinline__ float bf2f(unsigned short s) {
    return __uint_as_float(((u32)s) << 16);
}

// ws layout (after hs): pairs[2][H] (16 KB), epoch[2][8] replicas 128B apart (2 KB).
// pairs[parity][u] = (tag<<32)|f32bits, tag T == h after T steps (h_T; h_0 = 0).
// Sequencer WG polls all 1024 pair tags; when step-t complete it stores epoch
// replicas = t. Consumers spin on ONE wave-uniform epoch replica (1 txn/wave),
// then one-shot read the 1024 pairs. Race-free: overwrite of parity-t pairs
// (tag t+2, end of iter t+1) needs epoch t+1, which needs every WG to have
// published t+1, which happens only after that WG fully read parity-t pairs.
// NOTE reference hs[t] = h_{t+1} (tag t+1). hsh at iter t holds tag-t values
// = reference hs[t-1] -> rotating writer stores row t-1; final row via publish.
__global__ __launch_bounds__(256, 1)
void gru_rec_kernel(const float* __restrict__ X,
                    const float* __restrict__ Wih,
                    const float* __restrict__ Whh,
                    const float* __restrict__ bih,
                    const float* __restrict__ bhh,
                    float* __restrict__ hs,
                    u64* __restrict__ pairs)
{
    __shared__ unsigned short sWhh[3][UPW][H];      // 24 KB
    __shared__ unsigned short sWih[3][UPW][IN_DIM]; // 12 KB
    __shared__ float hsh[H];                        // 4 KB

    const int tid  = threadIdx.x;
    u64* const epoch = pairs + 2 * H;

    // ---------------- sequencer WG ----------------
    if (blockIdx.x == NBLK) {
        const int base = tid * 4;
        #pragma unroll 1
        for (int t = 0; t < T_LEN; ++t) {
            u64* pp = pairs + (size_t)(t & 1) * H;
            const u32 want = (u32)t;
            for (;;) {
                u64 p0 = __hip_atomic_load(pp + base + 0, __ATOMIC_RELAXED, __HIP_MEMORY_SCOPE_AGENT);
                u64 p1 = __hip_atomic_load(pp + base + 1, __ATOMIC_RELAXED, __HIP_MEMORY_SCOPE_AGENT);
                u64 p2 = __hip_atomic_load(pp + base + 2, __ATOMIC_RELAXED, __HIP_MEMORY_SCOPE_AGENT);
                u64 p3 = __hip_atomic_load(pp + base + 3, __ATOMIC_RELAXED, __HIP_MEMORY_SCOPE_AGENT);
                if ((u32)(p0 >> 32) == want && (u32)(p1 >> 32) == want &&
                    (u32)(p2 >> 32) == want && (u32)(p3 >> 32) == want) break;
            }
            __syncthreads();          // all 1024 tags of step t confirmed
            if (tid < 8)
                __hip_atomic_store(epoch + ((size_t)(t & 1) * 8 + tid) * 16, (u64)(u32)t,
                                   __ATOMIC_RELAXED, __HIP_MEMORY_SCOPE_AGENT);
        }
        return;
    }

    // ---------------- compute WGs ----------------
    const int wave = tid >> 6;
    const int lane = tid & 63;
    const int wg   = blockIdx.x;
    const int u0   = wg * UPW;
    const int u    = u0 + wave;

    // stage weights into LDS (bf16)
    for (int r = 0; r < 3 * UPW; ++r) {
        const int g = r >> 2, i = r & 3;
        const size_t grow = (size_t)g * H + (size_t)(u0 + i);
        float4 v = ((const float4*)(Whh + grow * H))[tid];
        unsigned short* dh = &sWhh[g][i][tid * 4];
        dh[0] = f2bf(v.x); dh[1] = f2bf(v.y); dh[2] = f2bf(v.z); dh[3] = f2bf(v.w);
        if (tid < 128) {
            float4 w = ((const float4*)(Wih + grow * IN_DIM))[tid];
            unsigned short* dx = &sWih[g][i][tid * 4];
            dx[0] = f2bf(w.x); dx[1] = f2bf(w.y); dx[2] = f2bf(w.z); dx[3] = f2bf(w.w);
        }
    }
    const float bxr = bih[u],       bxz = bih[H + u],     bxn = bih[2 * H + u];
    const float bhr = bhh[u],       bhz = bhh[H + u],     bhn = bhh[2 * H + u];
    __syncthreads();

    // prefetch x row for t=0
    float xv[8], xw[8];
    {
        const float4* xp = (const float4*)X;
        float4 a = xp[lane * 2], b = xp[lane * 2 + 1];
        xv[0]=a.x; xv[1]=a.y; xv[2]=a.z; xv[3]=a.w;
        xv[4]=b.x; xv[5]=b.y; xv[6]=b.z; xv[7]=b.w;
    }

    const int rdi  = ((tid + wg) & 255) * 4;  // staggered pair-read base (anti-convoy)
    const int hoff = lane * 16;
    const int xoff = lane * 8;
    u64* const ew  = epoch + ((wg & 7)) * 16;

    #pragma unroll 1
    for (int t = 0; t < T_LEN; ++t) {
        // prefetch next x row (in flight during the wait)
        {
            const int tn = (t + 1 < T_LEN) ? (t + 1) : t;
            const float4* xp = (const float4*)(X + (size_t)tn * IN_DIM);
            float4 a = xp[lane * 2], b = xp[lane * 2 + 1];
            xw[0]=a.x; xw[1]=a.y; xw[2]=a.z; xw[3]=a.w;
            xw[4]=b.x; xw[5]=b.y; xw[6]=b.z; xw[7]=b.w;
        }

        // ---- wait on epoch (wave-uniform address: 1 txn per wave per sweep) ----
        const u32 want = (u32)t;
        u64* ewp = ew + (size_t)(t & 1) * 8 * 16;
        while ((u32)__hip_atomic_load(ewp, __ATOMIC_RELAXED, __HIP_MEMORY_SCOPE_AGENT) != want) {}
        __builtin_amdgcn_sched_barrier(0);

        // ---- one-shot read of my 4 pairs (verify tags; passes first try) ----
        u64* pp = pairs + (size_t)(t & 1) * H;
        u64 p0, p1, p2, p3;
        for (;;) {
            p0 = __hip_atomic_load(pp + rdi + 0, __ATOMIC_RELAXED, __HIP_MEMORY_SCOPE_AGENT);
            p1 = __hip_atomic_load(pp + rdi + 1, __ATOMIC_RELAXED, __HIP_MEMORY_SCOPE_AGENT);
            p2 = __hip_atomic_load(pp + rdi + 2, __ATOMIC_RELAXED, __HIP_MEMORY_SCOPE_AGENT);
            p3 = __hip_atomic_load(pp + rdi + 3, __ATOMIC_RELAXED, __HIP_MEMORY_SCOPE_AGENT);
            if ((u32)(p0 >> 32) == want && (u32)(p1 >> 32) == want &&
                (u32)(p2 >> 32) == want && (u32)(p3 >> 32) == want) break;
        }
        {
            float4 hv4 = make_float4(__uint_as_float((u32)p0), __uint_as_float((u32)p1),
                                     __uint_as_float((u32)p2), __uint_as_float((u32)p3));
            *(float4*)&hsh[rdi] = hv4;
        }
        __syncthreads();   // hsh complete

        // coalesced store of PREVIOUS hs row (hsh == tag t == reference hs[t-1])
        if (t && wg == (t & 255)) {
            float4 hv4 = *(const float4*)&hsh[tid * 4];
            *(float4*)(hs + (size_t)(t - 1) * H + tid * 4) = hv4;
        }

        // gather my 16 h values
        float hv[16];
        #pragma unroll
        for (int i = 0; i < 4; ++i) {
            float4 h4 = *(const float4*)&hsh[hoff + i * 4];
            hv[i*4+0]=h4.x; hv[i*4+1]=h4.y; hv[i*4+2]=h4.z; hv[i*4+3]=h4.w;
        }

        // partial dots: gh (3 gates x 16 cols) + gx (3 gates x 8 cols)
        float ar = 0.f, az = 0.f, anh = 0.f, anx = 0.f;
        {
            const ushort8 r0 = *(const ushort8*)&sWhh[0][wave][hoff];
            const ushort8 r1 = *(const ushort8*)&sWhh[0][wave][hoff + 8];
            const ushort8 z0 = *(const ushort8*)&sWhh[1][wave][hoff];
            const ushort8 z1 = *(const ushort8*)&sWhh[1][wave][hoff + 8];
            const ushort8 n0 = *(const ushort8*)&sWhh[2][wave][hoff];
            const ushort8 n1 = *(const ushort8*)&sWhh[2][wave][hoff + 8];
            #pragma unroll
            for (int i = 0; i < 8; ++i) {
                ar  += bf2f(r0[i]) * hv[i];     ar  += bf2f(r1[i]) * hv[8 + i];
                az  += bf2f(z0[i]) * hv[i];     az  += bf2f(z1[i]) * hv[8 + i];
                anh += bf2f(n0[i]) * hv[i];     anh += bf2f(n1[i]) * hv[8 + i];
            }
            const ushort8 xr = *(const ushort8*)&sWih[0][wave][xoff];
            const ushort8 xz = *(const ushort8*)&sWih[1][wave][xoff];
            const ushort8 xn = *(const ushort8*)&sWih[2][wave][xoff];
            #pragma unroll
            for (int i = 0; i < 8; ++i) {
                ar  += bf2f(xr[i]) * xv[i];
                az  += bf2f(xz[i]) * xv[i];
                anx += bf2f(xn[i]) * xv[i];
            }
        }

        // wave reduction
        #pragma unroll
        for (int off = 32; off > 0; off >>= 1) {
            ar  += __shfl_xor(ar,  off, 64);
            az  += __shfl_xor(az,  off, 64);
            anh += __shfl_xor(anh, off, 64);
            anx += __shfl_xor(anx, off, 64);
        }

        // gates + publish (lane 0 of each wave)
        if (lane == 0) {
            const float hprev = hsh[u];
            const float r = 1.f / (1.f + __expf(-(ar + bxr + bhr)));
            const float z = 1.f / (1.f + __expf(-(az + bxz + bhz)));
            const float n = tanhf(anx + bxn + r * (anh + bhn));
            const float hnew = (1.f - z) * n + z * hprev;
            const u64 pk = ((u64)(u32)(t + 1) << 32) | (u64)__float_as_uint(hnew);
            __hip_atomic_store(pairs + (size_t)((t + 1) & 1) * H + u, pk,
                               __ATOMIC_RELAXED, __HIP_MEMORY_SCOPE_AGENT);
            if (t == T_LEN - 1)                 // final row: tag T_LEN never re-read
                hs[(size_t)t * H + u] = hnew;   // = reference hs[T_LEN-1]
        }
        __syncthreads();   // protect hsh before next-iteration overwrite

        #pragma unroll
        for (int i = 0; i < 8; ++i) xv[i] = xw[i];
    }
}

// out[m,n] = sum_k hs[m,k] * Wfc[n,k] + bfc[n]   (M=16384, N=512, K=1024)
#define BM 64
#define BN 64
#define BK 16
__global__ __launch_bounds__(256)
void fc_kernel(const float* __restrict__ A, const float* __restrict__ B,
               const float* __restrict__ bias, float* __restrict__ C)
{
    __shared__ float As[BK][BM + 4];
    __shared__ float Bs[BK][BN + 4];
    const int tid = threadIdx.x;
    const int m0 = blockIdx.y * BM, n0 = blockIdx.x * BN;
    const int tx = tid & 15, ty = tid >> 4;
    float acc[4][4] = {};
    const int r = tid >> 2, c = (tid & 3) << 2;
    for (int k0 = 0; k0 < H; k0 += BK) {
        float4 va = *(const float4*)(A + (size_t)(m0 + r) * H + (k0 + c));
        As[c + 0][r] = va.x; As[c + 1][r] = va.y; As[c + 2][r] = va.z; As[c + 3][r] = va.w;
        float4 vb = *(const float4*)(B + (size_t)(n0 + r) * H + (k0 + c));
        Bs[c + 0][r] = vb.x; Bs[c + 1][r] = vb.y; Bs[c + 2][r] = vb.z; Bs[c + 3][r] = vb.w;
        __syncthreads();
        #pragma unroll
        for (int kk = 0; kk < BK; ++kk) {
            float4 a4 = *(const float4*)&As[kk][ty * 4];
            float4 b4 = *(const float4*)&Bs[kk][tx * 4];
            const float av[4] = {a4.x, a4.y, a4.z, a4.w};
            const float bv[4] = {b4.x, b4.y, b4.z, b4.w};
            #pragma unroll
            for (int i = 0; i < 4; ++i)
                #pragma unroll
                for (int j = 0; j < 4; ++j)
                    acc[i][j] += av[i] * bv[j];
        }
        __syncthreads();
    }
    #pragma unroll
    for (int i = 0; i < 4; ++i) {
        const int m = m0 + ty * 4 + i;
        #pragma unroll
        for (int j = 0; j < 4; ++j) {
            const int n = n0 + tx * 4 + j;
            C[(size_t)m * OD + n] = acc[i][j] + bias[n];
        }
    }
}

extern "C" void kernel_launch(void* const* d_in, const int* in_sizes, int n_in,
                              void* d_out, int out_size, void* d_ws, size_t ws_size,
                              hipStream_t stream) {
    const float* X   = (const float*)d_in[0];
    const float* Wih = (const float*)d_in[1];
    const float* Whh = (const float*)d_in[2];
    const float* bih = (const float*)d_in[3];
    const float* bhh = (const float*)d_in[4];
    const float* Wfc = (const float*)d_in[5];
    const float* bfc = (const float*)d_in[6];
    float* out = (float*)d_out;

    float* hs    = (float*)d_ws;                                  // 64 MB
    u64*   pairs = (u64*)((char*)d_ws + (size_t)T_LEN * H * 4);   // 16 KB + epoch 2 KB

    // pairs: tag 0 / value 0.0 == initial hidden state; epoch[0]=0 == step 0 ready
    hipMemsetAsync(pairs, 0, 2 * H * sizeof(u64) + 2 * 8 * 16 * sizeof(u64), stream);

    void* args[] = { (void*)&X, (void*)&Wih, (void*)&Whh, (void*)&bih,
                     (void*)&bhh, (void*)&hs, (void*)&pairs };
    hipError_t e = hipLaunchCooperativeKernel((const void*)gru_rec_kernel,
                                              dim3(NBLK + 1), dim3(256), args, 0, stream);
    if (e != hipSuccess) {
        gru_rec_kernel<<<dim3(NBLK + 1), dim3(256), 0, stream>>>(X, Wih, Whh, bih, bhh, hs, pairs);
    }

    dim3 fgrid(OD / BN, T_LEN / BM);
    fc_kernel<<<fgrid, dim3(256), 0, stream>>>(hs, Wfc, bfc, out);
}